// Round 2
// baseline (475.494 us; speedup 1.0000x reference)
//
#include <hip/hip_runtime.h>
#include <cstdint>
#include <cstddef>

#define NH 8
#define LQ 2048
#define DH 64
#define NKT_HALF 16   // split-k: each block does 16 of the 32 k-tiles

typedef __attribute__((ext_vector_type(8))) __bf16 bf16x8;
typedef __attribute__((ext_vector_type(8))) unsigned short ushort8;
typedef __attribute__((ext_vector_type(4))) float floatx4;

__device__ __forceinline__ unsigned short bf_trunc(float x) {
    return (unsigned short)(__float_as_uint(x) >> 16);
}
__device__ __forceinline__ float bf_up(unsigned short h) {
    return __uint_as_float(((unsigned int)h) << 16);
}
__device__ __forceinline__ unsigned short bf_rne(float x) {
    unsigned int u = __float_as_uint(x);
    return (unsigned short)((u + 0x7FFFu + ((u >> 16) & 1u)) >> 16);
}
struct hl_t { unsigned short h, l; };
// x ~= h + l with |x-h-l| <= 2^-16 |x|
__device__ __forceinline__ hl_t split2(float x) {
    hl_t r;
    r.h = bf_trunc(x);
    r.l = bf_trunc(x - bf_up(r.h));
    return r;
}

#define MFMA16(A, B, C) __builtin_amdgcn_mfma_f32_16x16x32_bf16((A), (B), (C), 0, 0, 0)

// Grid: 512 = 32 qt * 8 h * 2 half. Block: 256 thr (4 waves, 16 q-rows each).
// Phase 1: writes unnormalized e=exp(s-8) to probs, PV/l partials to ws.
// Pair barrier (device-scope atomic) between the two halves of each (qt,h).
// Phase 2: each block rescales its OWN probs half in place (L2/L3-hot);
//          half-0 blocks combine PV partials -> out. No separate kernels.
__global__ __launch_bounds__(256, 3) void attn_main(
    const float* __restrict__ qp,  const float* __restrict__ kp,
    const float* __restrict__ vp,  const float* __restrict__ cp,
    const float* __restrict__ dqp, const float* __restrict__ dktp,
    const float* __restrict__ dkbp,const float* __restrict__ dksp,
    const float* __restrict__ rtp, const float* __restrict__ rbp,
    const float* __restrict__ Wwp, const float* __restrict__ Wbp,
    float* __restrict__ probp, float* __restrict__ lws, float* __restrict__ pvws,
    unsigned int* __restrict__ cnt, float* __restrict__ outp)
{
    // 40960 B total -> 4 blocks/CU by LDS
    __shared__ unsigned short sh_khi[64 * 72];   // Q-hi staging, then K-hi
    __shared__ unsigned short sh_klo[64 * 72];   // Q-lo staging, then K-lo, then ebf (P tile bf16)
    __shared__ unsigned short sh_vhi[64 * 72];   // V^T hi (c folded in)
    __shared__ unsigned short sh_vlo[64 * 72];   // V^T lo
    __shared__ float sh_meta[64 * 13];
    __shared__ float sh_dqs[64 * 3];

    const int bid  = blockIdx.x;
    const int half = bid & 1;
    const int h    = (bid >> 1) & 7;
    const int qt   = bid >> 4;
    const int q0   = qt * 64;
    const int t    = threadIdx.x;
    const int lane = t & 63;
    const int m    = lane & 15;
    const int quad = lane >> 4;
    const int w16  = (t >> 6) * 16;

    float Ww[4], Wb[4];
#pragma unroll
    for (int f = 0; f < 4; ++f) { Ww[f] = Wwp[f * NH + h]; Wb[f] = Wbp[f * NH + h]; }

    // ---- stage Q (hi/lo) into the K buffers, load dqs ----
    {
        const int row = t >> 2, s = t & 3;
        const float* src = qp + ((size_t)(h * LQ + q0 + row)) * DH + s * 16;
        ushort8 vh0, vh1, vl0, vl1;
#pragma unroll
        for (int j = 0; j < 2; ++j) {
            float4 x = *(const float4*)(src + 4 * j);
            hl_t a = split2(x.x), b = split2(x.y), c = split2(x.z), d = split2(x.w);
            vh0[4 * j + 0] = a.h; vl0[4 * j + 0] = a.l;
            vh0[4 * j + 1] = b.h; vl0[4 * j + 1] = b.l;
            vh0[4 * j + 2] = c.h; vl0[4 * j + 2] = c.l;
            vh0[4 * j + 3] = d.h; vl0[4 * j + 3] = d.l;
        }
#pragma unroll
        for (int j = 0; j < 2; ++j) {
            float4 x = *(const float4*)(src + 8 + 4 * j);
            hl_t a = split2(x.x), b = split2(x.y), c = split2(x.z), d = split2(x.w);
            vh1[4 * j + 0] = a.h; vl1[4 * j + 0] = a.l;
            vh1[4 * j + 1] = b.h; vl1[4 * j + 1] = b.l;
            vh1[4 * j + 2] = c.h; vl1[4 * j + 2] = c.l;
            vh1[4 * j + 3] = d.h; vl1[4 * j + 3] = d.l;
        }
        const int base = row * 72 + s * 16;
        *(ushort8*)&sh_khi[base] = vh0;  *(ushort8*)&sh_khi[base + 8] = vh1;
        *(ushort8*)&sh_klo[base] = vl0;  *(ushort8*)&sh_klo[base + 8] = vl1;
        if (t < 64) {
            sh_dqs[t * 3 + 0] = dqp[(q0 + t) * 3 + 0];
            sh_dqs[t * 3 + 1] = dqp[(q0 + t) * 3 + 1];
            sh_dqs[t * 3 + 2] = dqp[(q0 + t) * 3 + 2];
        }
    }
    __syncthreads();

    // Q A-fragments live in registers for the whole kernel
    bf16x8 aqh[2], aql[2];
#pragma unroll
    for (int kc = 0; kc < 2; ++kc) {
        aqh[kc] = *(const bf16x8*)&sh_khi[(w16 + m) * 72 + kc * 32 + quad * 8];
        aql[kc] = *(const bf16x8*)&sh_klo[(w16 + m) * 72 + kc * 32 + quad * 8];
    }
    float dq0[4], dq1[4], dq2[4];
#pragma unroll
    for (int r = 0; r < 4; ++r) {
        const int row = w16 + quad * 4 + r;
        dq0[r] = sh_dqs[row * 3 + 0]; dq1[r] = sh_dqs[row * 3 + 1]; dq2[r] = sh_dqs[row * 3 + 2];
    }
    __syncthreads();   // Q buffers free for K staging

    const floatx4 zf = {0.f, 0.f, 0.f, 0.f};
    floatx4 pacc[4] = {zf, zf, zf, zf};
    float lpart[4] = {0.f, 0.f, 0.f, 0.f};

    for (int kth = 0; kth < NKT_HALF; ++kth) {
        const int k0 = (half * NKT_HALF + kth) * 64;

        // ---- stage K (hi/lo, row-major) ----
        {
            const int row = t >> 2, s = t & 3;
            const float* src = kp + ((size_t)(h * LQ + k0 + row)) * DH + s * 16;
            ushort8 vh0, vh1, vl0, vl1;
#pragma unroll
            for (int j = 0; j < 2; ++j) {
                float4 x = *(const float4*)(src + 4 * j);
                hl_t a = split2(x.x), b = split2(x.y), c = split2(x.z), d = split2(x.w);
                vh0[4 * j + 0] = a.h; vl0[4 * j + 0] = a.l;
                vh0[4 * j + 1] = b.h; vl0[4 * j + 1] = b.l;
                vh0[4 * j + 2] = c.h; vl0[4 * j + 2] = c.l;
                vh0[4 * j + 3] = d.h; vl0[4 * j + 3] = d.l;
            }
#pragma unroll
            for (int j = 0; j < 2; ++j) {
                float4 x = *(const float4*)(src + 8 + 4 * j);
                hl_t a = split2(x.x), b = split2(x.y), c = split2(x.z), d = split2(x.w);
                vh1[4 * j + 0] = a.h; vl1[4 * j + 0] = a.l;
                vh1[4 * j + 1] = b.h; vl1[4 * j + 1] = b.l;
                vh1[4 * j + 2] = c.h; vl1[4 * j + 2] = c.l;
                vh1[4 * j + 3] = d.h; vl1[4 * j + 3] = d.l;
            }
            const int base = row * 72 + s * 16;
            *(ushort8*)&sh_khi[base] = vh0;  *(ushort8*)&sh_khi[base + 8] = vh1;
            *(ushort8*)&sh_klo[base] = vl0;  *(ushort8*)&sh_klo[base + 8] = vl1;
        }
        // ---- stage V transposed (hi/lo), c folded in; packed b32 writes (conflict-free) ----
        {
            const int p = t >> 4;    // 0..15 -> kk pair
            const int mm = t & 15;
#pragma unroll
            for (int g = 0; g < 2; ++g) {
                const int kka = 2 * p + 32 * g;
                const float ca = cp[k0 + kka], cb = cp[k0 + kka + 1];
                const float* va = vp + ((size_t)(h * LQ + k0 + kka)) * DH;
                const float* vb = va + DH;
#pragma unroll
                for (int dd = 0; dd < 4; ++dd) {
                    const int d = mm + 16 * dd;
                    hl_t xa = split2(va[d] * ca);
                    hl_t xb = split2(vb[d] * cb);
                    *(unsigned int*)&sh_vhi[d * 72 + kka] = (unsigned int)xa.h | ((unsigned int)xb.h << 16);
                    *(unsigned int*)&sh_vlo[d * 72 + kka] = (unsigned int)xa.l | ((unsigned int)xb.l << 16);
                }
            }
        }
        // ---- per-k folded bias coefficients ----
        if (t < 64) {
            const int kg = k0 + t;
            const float* sc_ = dksp + (size_t)kg * 8;   // [2][4] top then bottom
            const float* tp  = dktp + (size_t)kg * 3;
            const float* bt  = dkbp + (size_t)kg * 3;
            float cw = 0.f, cb2 = 0.f;
#pragma unroll
            for (int f = 0; f < 3; ++f) {
                const float stf = sc_[f], sbf = sc_[4 + f];
                const float A  = stf + sbf;
                const float Bv = tp[f] * stf + bt[f] * sbf;
                sh_meta[t * 13 + f]     = A * Ww[f];
                sh_meta[t * 13 + 4 + f] = A * Wb[f];
                cw  -= Bv * Ww[f];
                cb2 -= Bv * Wb[f];
            }
            sh_meta[t * 13 + 3]  = cw;              sh_meta[t * 13 + 7]  = cb2;
            sh_meta[t * 13 + 8]  = sc_[3] * Ww[3];  sh_meta[t * 13 + 9]  = sc_[7] * Ww[3];
            sh_meta[t * 13 + 10] = sc_[3] * Wb[3];  sh_meta[t * 13 + 11] = sc_[7] * Wb[3];
        }
        __syncthreads();

        // ---- prefetch rel features (hidden behind MFMA phase) ----
        float rt_[4][4], rb_[4][4];
#pragma unroll
        for (int r = 0; r < 4; ++r) {
            const size_t q = (size_t)(q0 + w16 + quad * 4 + r);
#pragma unroll
            for (int nt = 0; nt < 4; ++nt) {
                rt_[nt][r] = rtp[q * LQ + k0 + nt * 16 + m];
                rb_[nt][r] = rbp[q * LQ + k0 + nt * 16 + m];
            }
        }

        // ---- QK^T: 3-term split-bf16 MFMA ----
        floatx4 sc[4] = {zf, zf, zf, zf};
#pragma unroll
        for (int nt = 0; nt < 4; ++nt) {
#pragma unroll
            for (int kc = 0; kc < 2; ++kc) {
                const int kb = (nt * 16 + m) * 72 + kc * 32 + quad * 8;
                bf16x8 bh = *(const bf16x8*)&sh_khi[kb];
                bf16x8 bl = *(const bf16x8*)&sh_klo[kb];
                sc[nt] = MFMA16(aqh[kc], bh, sc[nt]);
                sc[nt] = MFMA16(aql[kc], bh, sc[nt]);
                sc[nt] = MFMA16(aqh[kc], bl, sc[nt]);
            }
        }
        __syncthreads();   // all waves done with K-lo -> reuse as ebf

        // ---- epilogue: gate + bias + exp; probs store; P->LDS (bf16, A-layout rows) ----
        unsigned short* ebf = sh_klo;
#pragma unroll
        for (int nt = 0; nt < 4; ++nt) {
            const int kcol = nt * 16 + m;
            const float m0 = sh_meta[kcol * 13 + 0],  m1 = sh_meta[kcol * 13 + 1];
            const float m2 = sh_meta[kcol * 13 + 2],  m3 = sh_meta[kcol * 13 + 3];
            const float m4 = sh_meta[kcol * 13 + 4],  m5 = sh_meta[kcol * 13 + 5];
            const float m6 = sh_meta[kcol * 13 + 6],  m7 = sh_meta[kcol * 13 + 7];
            const float m8 = sh_meta[kcol * 13 + 8],  m9 = sh_meta[kcol * 13 + 9];
            const float mA = sh_meta[kcol * 13 + 10], mB = sh_meta[kcol * 13 + 11];
#pragma unroll
            for (int r = 0; r < 4; ++r) {
                float ww = fmaf(dq0[r], m0, m3); ww = fmaf(dq1[r], m1, ww); ww = fmaf(dq2[r], m2, ww);
                ww = fmaf(rt_[nt][r], m8, ww);   ww = fmaf(rb_[nt][r], m9, ww);
                float bb = fmaf(dq0[r], m4, m7); bb = fmaf(dq1[r], m5, bb); bb = fmaf(dq2[r], m6, bb);
                bb = fmaf(rt_[nt][r], mA, bb);   bb = fmaf(rb_[nt][r], mB, bb);
                const float wg = fmaxf(ww, 0.f) + __logf(1.f + __expf(-fabsf(ww)));
                const float sv = fmaf(sc[nt][r] * 0.125f, wg, bb);
                const float e  = __expf(sv - 8.0f);   // constant shift cancels in normalization
                lpart[r] += e;
                probp[((size_t)(h * LQ + q0 + w16 + quad * 4 + r)) * LQ + k0 + kcol] = e;
                ebf[(w16 + quad * 4 + r) * 72 + kcol] = bf_rne(e);
            }
        }

        // ---- PV: bf16 P x split-bf16 V (own-wave rows; no barrier needed before reads) ----
        bf16x8 ap0 = *(const bf16x8*)&ebf[(w16 + m) * 72 + quad * 8];
        bf16x8 ap1 = *(const bf16x8*)&ebf[(w16 + m) * 72 + 32 + quad * 8];
#pragma unroll
        for (int nt = 0; nt < 4; ++nt) {
            const int vb = (nt * 16 + m) * 72 + quad * 8;
            bf16x8 bh0 = *(const bf16x8*)&sh_vhi[vb];
            bf16x8 bl0 = *(const bf16x8*)&sh_vlo[vb];
            bf16x8 bh1 = *(const bf16x8*)&sh_vhi[vb + 32];
            bf16x8 bl1 = *(const bf16x8*)&sh_vlo[vb + 32];
            pacc[nt] = MFMA16(ap0, bh0, pacc[nt]);
            pacc[nt] = MFMA16(ap0, bl0, pacc[nt]);
            pacc[nt] = MFMA16(ap1, bh1, pacc[nt]);
            pacc[nt] = MFMA16(ap1, bl1, pacc[nt]);
        }
        __syncthreads();   // ebf/vT consumed before next staging
    }

    // ---- row-sum partials: reduce over the 16 m-lanes (quad-local via shfl_xor) ----
#pragma unroll
    for (int off = 1; off < 16; off <<= 1) {
#pragma unroll
        for (int r = 0; r < 4; ++r) lpart[r] += __shfl_xor(lpart[r], off, 64);
    }
    if (m == 0) {
#pragma unroll
        for (int r = 0; r < 4; ++r)
            lws[half * (NH * LQ) + h * LQ + q0 + w16 + quad * 4 + r] = lpart[r];
    }
    // ---- PV partials to ws ----
#pragma unroll
    for (int nt = 0; nt < 4; ++nt) {
#pragma unroll
        for (int r = 0; r < 4; ++r) {
            const size_t row = (size_t)(h * LQ + q0 + w16 + quad * 4 + r);
            pvws[(size_t)half * (NH * LQ * DH) + row * DH + nt * 16 + m] = pacc[nt][r];
        }
    }

    // ================= pair barrier: wait for the other half =================
    __threadfence();          // make probs/lws/pvws visible at device scope
    __syncthreads();          // all threads of this block have fenced
    if (t == 0) {
        __hip_atomic_fetch_add(&cnt[bid >> 1], 1u, __ATOMIC_RELEASE, __HIP_MEMORY_SCOPE_AGENT);
        while (__hip_atomic_load(&cnt[bid >> 1], __ATOMIC_ACQUIRE, __HIP_MEMORY_SCOPE_AGENT) < 2u) {
            __builtin_amdgcn_s_sleep(8);
        }
    }
    __syncthreads();
    __threadfence();          // acquire partner's writes for all threads

    // ================= phase 2a: rl per row into LDS =================
    if (t < 64) {
        const int row = h * LQ + q0 + t;
        sh_dqs[t] = 1.0f / (lws[row] + lws[NH * LQ + row]);
    }
    __syncthreads();

    // ================= phase 2b: rescale OWN probs half in place (L2-hot) =====
    {
        const float4 c4 = *(const float4*)(cp + half * 1024 + (t << 2));
        float* pbase = probp + ((size_t)(h * LQ + q0)) * LQ + half * 1024 + (t << 2);
#pragma unroll 4
        for (int r = 0; r < 64; ++r) {
            const float rl = sh_dqs[r];
            float4 x = *(const float4*)(pbase + (size_t)r * LQ);
            x.x *= rl * c4.x; x.y *= rl * c4.y; x.z *= rl * c4.z; x.w *= rl * c4.w;
            *(float4*)(pbase + (size_t)r * LQ) = x;
        }
    }

    // ================= phase 2c: half-0 blocks combine PV -> out =============
    if (half == 0) {
        const int r  = t >> 2;
        const int cs = (t & 3) * 16;
        const size_t row = (size_t)(h * LQ + q0 + r);
        const float rl = sh_dqs[r];
#pragma unroll
        for (int j = 0; j < 4; ++j) {
            float4 a = *(const float4*)(pvws + row * DH + cs + 4 * j);
            float4 b = *(const float4*)(pvws + (size_t)(NH * LQ * DH) + row * DH + cs + 4 * j);
            *(float4*)(outp + row * DH + cs + 4 * j) =
                make_float4((a.x + b.x) * rl, (a.y + b.y) * rl, (a.z + b.z) * rl, (a.w + b.w) * rl);
        }
    }
}

extern "C" void kernel_launch(void* const* d_in, const int* in_sizes, int n_in,
                              void* d_out, int out_size, void* d_ws, size_t ws_size,
                              hipStream_t stream)
{
    (void)in_sizes; (void)n_in; (void)ws_size; (void)out_size;
    const float* qp   = (const float*)d_in[0];
    const float* kp   = (const float*)d_in[1];
    const float* vp   = (const float*)d_in[2];
    const float* cp   = (const float*)d_in[3];
    const float* dqp  = (const float*)d_in[4];
    const float* dktp = (const float*)d_in[5];
    const float* dkbp = (const float*)d_in[6];
    const float* dksp = (const float*)d_in[7];
    const float* rtp  = (const float*)d_in[8];
    const float* rbp  = (const float*)d_in[9];
    const float* Wwp  = (const float*)d_in[10];
    const float* Wbp  = (const float*)d_in[11];

    float* outp  = (float*)d_out;                            // [1,8,2048,64]
    float* probp = (float*)d_out + (size_t)NH * LQ * DH;     // [1,8,2048,2048]

    float* lws  = (float*)d_ws;                              // [2][16384]
    float* pvws = (float*)d_ws + 2 * (NH * LQ);              // [2][16384*64]
    unsigned int* cnt = (unsigned int*)(pvws + (size_t)2 * (NH * LQ * DH));  // [256]

    hipMemsetAsync(cnt, 0, 256 * sizeof(unsigned int), stream);

    attn_main<<<dim3(512), dim3(256), 0, stream>>>(
        qp, kp, vp, cp, dqp, dktp, dkbp, dksp, rtp, rbp, Wwp, Wbp, probp, lws, pvws, cnt, outp);
}

// Round 3
// 330.128 us; speedup vs baseline: 1.4403x; 1.4403x over previous
//
#include <hip/hip_runtime.h>
#include <cstdint>
#include <cstddef>

#define NH 8
#define LQ 2048
#define DH 64

typedef __attribute__((ext_vector_type(8))) __bf16 bf16x8;
typedef __attribute__((ext_vector_type(8))) unsigned short ushort8;
typedef __attribute__((ext_vector_type(4))) float floatx4;

__device__ __forceinline__ unsigned short bf_trunc(float x) {
    return (unsigned short)(__float_as_uint(x) >> 16);
}
__device__ __forceinline__ float bf_up(unsigned short h) {
    return __uint_as_float(((unsigned int)h) << 16);
}
__device__ __forceinline__ unsigned short bf_rne(float x) {
    unsigned int u = __float_as_uint(x);
    return (unsigned short)((u + 0x7FFFu + ((u >> 16) & 1u)) >> 16);
}
struct hl_t { unsigned short h, l; };
// x ~= h + l with |x-h-l| <= 2^-16 |x|
__device__ __forceinline__ hl_t split2(float x) {
    hl_t r;
    r.h = bf_trunc(x);
    r.l = bf_trunc(x - bf_up(r.h));
    return r;
}

#define MFMA16(A, B, C) __builtin_amdgcn_mfma_f32_16x16x32_bf16((A), (B), (C), 0, 0, 0)

// Grid: 256*NSPLIT = 32 qt * 8 h * NSPLIT splits. Block: 256 thr (4 waves, 16 q-rows each).
// Writes unnormalized e=exp(s-8) to probs, PV/l partials to ws.
// NSPLIT=4 -> 1024 blocks. LDS = 40960 B -> 160KiB/40960 = exactly 4 blocks/CU.
// __launch_bounds__(256,3) NOT (256,4): the latter forces VGPR<=64 and SPILLS
// (round-1 evidence: VGPR 84->64, WRITE_SIZE +25MB scratch, dur +16%).
// At 84 VGPR the HW still fits 4 blocks/CU (16 waves/CU; VGPR halving is at 128).
template<int NSPLIT>
__global__ __launch_bounds__(256, 3) void attn_main(
    const float* __restrict__ qp,  const float* __restrict__ kp,
    const float* __restrict__ vp,  const float* __restrict__ cp,
    const float* __restrict__ dqp, const float* __restrict__ dktp,
    const float* __restrict__ dkbp,const float* __restrict__ dksp,
    const float* __restrict__ rtp, const float* __restrict__ rbp,
    const float* __restrict__ Wwp, const float* __restrict__ Wbp,
    float* __restrict__ probp, float* __restrict__ lws, float* __restrict__ pvws)
{
    constexpr int NKT = 32 / NSPLIT;   // k-tiles per block

    // 40960 B total -> 4 blocks/CU by LDS
    __shared__ unsigned short sh_khi[64 * 72];   // Q-hi staging, then K-hi
    __shared__ unsigned short sh_klo[64 * 72];   // Q-lo staging, then K-lo, then ebf (P tile bf16)
    __shared__ unsigned short sh_vhi[64 * 72];   // V^T hi (c folded in)
    __shared__ unsigned short sh_vlo[64 * 72];   // V^T lo
    __shared__ float sh_meta[64 * 13];
    __shared__ float sh_dqs[64 * 3];

    const int bid   = blockIdx.x;
    const int split = bid % NSPLIT;
    const int h     = (bid / NSPLIT) & 7;
    const int qt    = bid / (NSPLIT * 8);
    const int q0    = qt * 64;
    const int t     = threadIdx.x;
    const int lane  = t & 63;
    const int m     = lane & 15;
    const int quad  = lane >> 4;
    const int w16   = (t >> 6) * 16;

    float Ww[4], Wb[4];
#pragma unroll
    for (int f = 0; f < 4; ++f) { Ww[f] = Wwp[f * NH + h]; Wb[f] = Wbp[f * NH + h]; }

    // ---- stage Q (hi/lo) into the K buffers, load dqs ----
    {
        const int row = t >> 2, s = t & 3;
        const float* src = qp + ((size_t)(h * LQ + q0 + row)) * DH + s * 16;
        ushort8 vh0, vh1, vl0, vl1;
#pragma unroll
        for (int j = 0; j < 2; ++j) {
            float4 x = *(const float4*)(src + 4 * j);
            hl_t a = split2(x.x), b = split2(x.y), c = split2(x.z), d = split2(x.w);
            vh0[4 * j + 0] = a.h; vl0[4 * j + 0] = a.l;
            vh0[4 * j + 1] = b.h; vl0[4 * j + 1] = b.l;
            vh0[4 * j + 2] = c.h; vl0[4 * j + 2] = c.l;
            vh0[4 * j + 3] = d.h; vl0[4 * j + 3] = d.l;
        }
#pragma unroll
        for (int j = 0; j < 2; ++j) {
            float4 x = *(const float4*)(src + 8 + 4 * j);
            hl_t a = split2(x.x), b = split2(x.y), c = split2(x.z), d = split2(x.w);
            vh1[4 * j + 0] = a.h; vl1[4 * j + 0] = a.l;
            vh1[4 * j + 1] = b.h; vl1[4 * j + 1] = b.l;
            vh1[4 * j + 2] = c.h; vl1[4 * j + 2] = c.l;
            vh1[4 * j + 3] = d.h; vl1[4 * j + 3] = d.l;
        }
        const int base = row * 72 + s * 16;
        *(ushort8*)&sh_khi[base] = vh0;  *(ushort8*)&sh_khi[base + 8] = vh1;
        *(ushort8*)&sh_klo[base] = vl0;  *(ushort8*)&sh_klo[base + 8] = vl1;
        if (t < 64) {
            sh_dqs[t * 3 + 0] = dqp[(q0 + t) * 3 + 0];
            sh_dqs[t * 3 + 1] = dqp[(q0 + t) * 3 + 1];
            sh_dqs[t * 3 + 2] = dqp[(q0 + t) * 3 + 2];
        }
    }
    __syncthreads();

    // Q A-fragments live in registers for the whole kernel
    bf16x8 aqh[2], aql[2];
#pragma unroll
    for (int kc = 0; kc < 2; ++kc) {
        aqh[kc] = *(const bf16x8*)&sh_khi[(w16 + m) * 72 + kc * 32 + quad * 8];
        aql[kc] = *(const bf16x8*)&sh_klo[(w16 + m) * 72 + kc * 32 + quad * 8];
    }
    float dq0[4], dq1[4], dq2[4];
#pragma unroll
    for (int r = 0; r < 4; ++r) {
        const int row = w16 + quad * 4 + r;
        dq0[r] = sh_dqs[row * 3 + 0]; dq1[r] = sh_dqs[row * 3 + 1]; dq2[r] = sh_dqs[row * 3 + 2];
    }
    __syncthreads();   // Q buffers free for K staging

    const floatx4 zf = {0.f, 0.f, 0.f, 0.f};
    floatx4 pacc[4] = {zf, zf, zf, zf};
    float lpart[4] = {0.f, 0.f, 0.f, 0.f};

    for (int kth = 0; kth < NKT; ++kth) {
        const int k0 = (split * NKT + kth) * 64;

        // ---- stage K (hi/lo, row-major) ----
        {
            const int row = t >> 2, s = t & 3;
            const float* src = kp + ((size_t)(h * LQ + k0 + row)) * DH + s * 16;
            ushort8 vh0, vh1, vl0, vl1;
#pragma unroll
            for (int j = 0; j < 2; ++j) {
                float4 x = *(const float4*)(src + 4 * j);
                hl_t a = split2(x.x), b = split2(x.y), c = split2(x.z), d = split2(x.w);
                vh0[4 * j + 0] = a.h; vl0[4 * j + 0] = a.l;
                vh0[4 * j + 1] = b.h; vl0[4 * j + 1] = b.l;
                vh0[4 * j + 2] = c.h; vl0[4 * j + 2] = c.l;
                vh0[4 * j + 3] = d.h; vl0[4 * j + 3] = d.l;
            }
#pragma unroll
            for (int j = 0; j < 2; ++j) {
                float4 x = *(const float4*)(src + 8 + 4 * j);
                hl_t a = split2(x.x), b = split2(x.y), c = split2(x.z), d = split2(x.w);
                vh1[4 * j + 0] = a.h; vl1[4 * j + 0] = a.l;
                vh1[4 * j + 1] = b.h; vl1[4 * j + 1] = b.l;
                vh1[4 * j + 2] = c.h; vl1[4 * j + 2] = c.l;
                vh1[4 * j + 3] = d.h; vl1[4 * j + 3] = d.l;
            }
            const int base = row * 72 + s * 16;
            *(ushort8*)&sh_khi[base] = vh0;  *(ushort8*)&sh_khi[base + 8] = vh1;
            *(ushort8*)&sh_klo[base] = vl0;  *(ushort8*)&sh_klo[base + 8] = vl1;
        }
        // ---- stage V transposed (hi/lo), c folded in; packed b32 writes (conflict-free) ----
        {
            const int p = t >> 4;    // 0..15 -> kk pair
            const int mm = t & 15;
#pragma unroll
            for (int g = 0; g < 2; ++g) {
                const int kka = 2 * p + 32 * g;
                const float ca = cp[k0 + kka], cb = cp[k0 + kka + 1];
                const float* va = vp + ((size_t)(h * LQ + k0 + kka)) * DH;
                const float* vb = va + DH;
#pragma unroll
                for (int dd = 0; dd < 4; ++dd) {
                    const int d = mm + 16 * dd;
                    hl_t xa = split2(va[d] * ca);
                    hl_t xb = split2(vb[d] * cb);
                    *(unsigned int*)&sh_vhi[d * 72 + kka] = (unsigned int)xa.h | ((unsigned int)xb.h << 16);
                    *(unsigned int*)&sh_vlo[d * 72 + kka] = (unsigned int)xa.l | ((unsigned int)xb.l << 16);
                }
            }
        }
        // ---- per-k folded bias coefficients ----
        if (t < 64) {
            const int kg = k0 + t;
            const float* sc_ = dksp + (size_t)kg * 8;   // [2][4] top then bottom
            const float* tp  = dktp + (size_t)kg * 3;
            const float* bt  = dkbp + (size_t)kg * 3;
            float cw = 0.f, cb2 = 0.f;
#pragma unroll
            for (int f = 0; f < 3; ++f) {
                const float stf = sc_[f], sbf = sc_[4 + f];
                const float A  = stf + sbf;
                const float Bv = tp[f] * stf + bt[f] * sbf;
                sh_meta[t * 13 + f]     = A * Ww[f];
                sh_meta[t * 13 + 4 + f] = A * Wb[f];
                cw  -= Bv * Ww[f];
                cb2 -= Bv * Wb[f];
            }
            sh_meta[t * 13 + 3]  = cw;              sh_meta[t * 13 + 7]  = cb2;
            sh_meta[t * 13 + 8]  = sc_[3] * Ww[3];  sh_meta[t * 13 + 9]  = sc_[7] * Ww[3];
            sh_meta[t * 13 + 10] = sc_[3] * Wb[3];  sh_meta[t * 13 + 11] = sc_[7] * Wb[3];
        }
        __syncthreads();

        // ---- prefetch rel features (hidden behind MFMA phase) ----
        float rt_[4][4], rb_[4][4];
#pragma unroll
        for (int r = 0; r < 4; ++r) {
            const size_t q = (size_t)(q0 + w16 + quad * 4 + r);
#pragma unroll
            for (int nt = 0; nt < 4; ++nt) {
                rt_[nt][r] = rtp[q * LQ + k0 + nt * 16 + m];
                rb_[nt][r] = rbp[q * LQ + k0 + nt * 16 + m];
            }
        }

        // ---- QK^T: 3-term split-bf16 MFMA ----
        floatx4 sc[4] = {zf, zf, zf, zf};
#pragma unroll
        for (int nt = 0; nt < 4; ++nt) {
#pragma unroll
            for (int kc = 0; kc < 2; ++kc) {
                const int kb = (nt * 16 + m) * 72 + kc * 32 + quad * 8;
                bf16x8 bh = *(const bf16x8*)&sh_khi[kb];
                bf16x8 bl = *(const bf16x8*)&sh_klo[kb];
                sc[nt] = MFMA16(aqh[kc], bh, sc[nt]);
                sc[nt] = MFMA16(aql[kc], bh, sc[nt]);
                sc[nt] = MFMA16(aqh[kc], bl, sc[nt]);
            }
        }
        __syncthreads();   // all waves done with K-lo -> reuse as ebf

        // ---- epilogue: gate + bias + exp; probs store; P->LDS (bf16, A-layout rows) ----
        unsigned short* ebf = sh_klo;
#pragma unroll
        for (int nt = 0; nt < 4; ++nt) {
            const int kcol = nt * 16 + m;
            const float m0 = sh_meta[kcol * 13 + 0],  m1 = sh_meta[kcol * 13 + 1];
            const float m2 = sh_meta[kcol * 13 + 2],  m3 = sh_meta[kcol * 13 + 3];
            const float m4 = sh_meta[kcol * 13 + 4],  m5 = sh_meta[kcol * 13 + 5];
            const float m6 = sh_meta[kcol * 13 + 6],  m7 = sh_meta[kcol * 13 + 7];
            const float m8 = sh_meta[kcol * 13 + 8],  m9 = sh_meta[kcol * 13 + 9];
            const float mA = sh_meta[kcol * 13 + 10], mB = sh_meta[kcol * 13 + 11];
#pragma unroll
            for (int r = 0; r < 4; ++r) {
                float ww = fmaf(dq0[r], m0, m3); ww = fmaf(dq1[r], m1, ww); ww = fmaf(dq2[r], m2, ww);
                ww = fmaf(rt_[nt][r], m8, ww);   ww = fmaf(rb_[nt][r], m9, ww);
                float bb = fmaf(dq0[r], m4, m7); bb = fmaf(dq1[r], m5, bb); bb = fmaf(dq2[r], m6, bb);
                bb = fmaf(rt_[nt][r], mA, bb);   bb = fmaf(rb_[nt][r], mB, bb);
                const float wg = fmaxf(ww, 0.f) + __logf(1.f + __expf(-fabsf(ww)));
                const float sv = fmaf(sc[nt][r] * 0.125f, wg, bb);
                const float e  = __expf(sv - 8.0f);   // constant shift cancels in normalization
                lpart[r] += e;
                probp[((size_t)(h * LQ + q0 + w16 + quad * 4 + r)) * LQ + k0 + kcol] = e;
                ebf[(w16 + quad * 4 + r) * 72 + kcol] = bf_rne(e);
            }
        }

        // ---- PV: bf16 P x split-bf16 V (own-wave rows; no barrier needed before reads) ----
        bf16x8 ap0 = *(const bf16x8*)&ebf[(w16 + m) * 72 + quad * 8];
        bf16x8 ap1 = *(const bf16x8*)&ebf[(w16 + m) * 72 + 32 + quad * 8];
#pragma unroll
        for (int nt = 0; nt < 4; ++nt) {
            const int vb = (nt * 16 + m) * 72 + quad * 8;
            bf16x8 bh0 = *(const bf16x8*)&sh_vhi[vb];
            bf16x8 bl0 = *(const bf16x8*)&sh_vlo[vb];
            bf16x8 bh1 = *(const bf16x8*)&sh_vhi[vb + 32];
            bf16x8 bl1 = *(const bf16x8*)&sh_vlo[vb + 32];
            pacc[nt] = MFMA16(ap0, bh0, pacc[nt]);
            pacc[nt] = MFMA16(ap0, bl0, pacc[nt]);
            pacc[nt] = MFMA16(ap1, bh1, pacc[nt]);
            pacc[nt] = MFMA16(ap1, bl1, pacc[nt]);
        }
        __syncthreads();   // ebf/vT consumed before next staging
    }

    // ---- row-sum partials: reduce over the 16 m-lanes (quad-local via shfl_xor) ----
#pragma unroll
    for (int off = 1; off < 16; off <<= 1) {
#pragma unroll
        for (int r = 0; r < 4; ++r) lpart[r] += __shfl_xor(lpart[r], off, 64);
    }
    if (m == 0) {
#pragma unroll
        for (int r = 0; r < 4; ++r)
            lws[split * (NH * LQ) + h * LQ + q0 + w16 + quad * 4 + r] = lpart[r];
    }
    // ---- PV partials to ws ----
#pragma unroll
    for (int nt = 0; nt < 4; ++nt) {
#pragma unroll
        for (int r = 0; r < 4; ++r) {
            const size_t row = (size_t)(h * LQ + q0 + w16 + quad * 4 + r);
            pvws[(size_t)split * (NH * LQ * DH) + row * DH + nt * 16 + m] = pacc[nt][r];
        }
    }
}

// out = (sum_s pv_s) / (sum_s l_s)
__global__ void combine_kernel(const float* __restrict__ pvws, const float* __restrict__ lws,
                               float* __restrict__ outp, int nsplit)
{
    const int idx4 = blockIdx.x * 256 + threadIdx.x;   // 0..262143
    const int row  = idx4 >> 4;
    const int d4   = (idx4 & 15) * 4;
    float ax = 0.f, ay = 0.f, az = 0.f, aw = 0.f, l = 0.f;
    for (int s = 0; s < nsplit; ++s) {
        const float4 a = *(const float4*)(pvws + (size_t)s * (NH * LQ * DH) + (size_t)row * DH + d4);
        ax += a.x; ay += a.y; az += a.z; aw += a.w;
        l  += lws[s * (NH * LQ) + row];
    }
    const float rl = 1.0f / l;
    *(float4*)(outp + (size_t)row * DH + d4) = make_float4(ax * rl, ay * rl, az * rl, aw * rl);
}

// probs[row][k] = e[row][k] * c[k] / l[row]   (pure elementwise; l from ws)
__global__ void norm_kernel(float* __restrict__ probp, const float* __restrict__ cp,
                            const float* __restrict__ lws, int nsplit)
{
    const int row = blockIdx.x;
    float l = 0.f;
    for (int s = 0; s < nsplit; ++s) l += lws[s * (NH * LQ) + row];
    const float rl = 1.0f / l;
    float* p = probp + (size_t)row * LQ;
    const int t = threadIdx.x;
    float4 x0 = *(const float4*)(p + t * 4);
    float4 x1 = *(const float4*)(p + (t + 256) * 4);
    const float4 c0 = *(const float4*)(cp + t * 4);
    const float4 c1 = *(const float4*)(cp + (t + 256) * 4);
    x0.x *= rl * c0.x; x0.y *= rl * c0.y; x0.z *= rl * c0.z; x0.w *= rl * c0.w;
    x1.x *= rl * c1.x; x1.y *= rl * c1.y; x1.z *= rl * c1.z; x1.w *= rl * c1.w;
    *(float4*)(p + t * 4)         = x0;
    *(float4*)(p + (t + 256) * 4) = x1;
}

extern "C" void kernel_launch(void* const* d_in, const int* in_sizes, int n_in,
                              void* d_out, int out_size, void* d_ws, size_t ws_size,
                              hipStream_t stream)
{
    (void)in_sizes; (void)n_in; (void)out_size;
    const float* qp   = (const float*)d_in[0];
    const float* kp   = (const float*)d_in[1];
    const float* vp   = (const float*)d_in[2];
    const float* cp   = (const float*)d_in[3];
    const float* dqp  = (const float*)d_in[4];
    const float* dktp = (const float*)d_in[5];
    const float* dkbp = (const float*)d_in[6];
    const float* dksp = (const float*)d_in[7];
    const float* rtp  = (const float*)d_in[8];
    const float* rbp  = (const float*)d_in[9];
    const float* Wwp  = (const float*)d_in[10];
    const float* Wbp  = (const float*)d_in[11];

    float* outp  = (float*)d_out;                            // [1,8,2048,64]
    float* probp = (float*)d_out + (size_t)NH * LQ * DH;     // [1,8,2048,2048]

    // Workspace: nsplit * (l partials [NH*LQ] + pv partials [NH*LQ*DH])
    const size_t need4 = (size_t)4 * (NH * LQ) * sizeof(float)
                       + (size_t)4 * (NH * LQ * DH) * sizeof(float);   // ~16.9 MB
    const int nsplit = (ws_size >= need4) ? 4 : 2;

    float* lws  = (float*)d_ws;                              // [nsplit][16384]
    float* pvws = (float*)d_ws + (size_t)nsplit * (NH * LQ); // [nsplit][16384*64]

    if (nsplit == 4) {
        attn_main<4><<<dim3(1024), dim3(256), 0, stream>>>(
            qp, kp, vp, cp, dqp, dktp, dkbp, dksp, rtp, rbp, Wwp, Wbp, probp, lws, pvws);
    } else {
        attn_main<2><<<dim3(512), dim3(256), 0, stream>>>(
            qp, kp, vp, cp, dqp, dktp, dkbp, dksp, rtp, rbp, Wwp, Wbp, probp, lws, pvws);
    }
    combine_kernel<<<dim3(1024), dim3(256), 0, stream>>>(pvws, lws, outp, nsplit);
    norm_kernel<<<dim3(NH * LQ), dim3(256), 0, stream>>>(probp, cp, lws, nsplit);
}

// Round 4
// 287.288 us; speedup vs baseline: 1.6551x; 1.1491x over previous
//
#include <hip/hip_runtime.h>
#include <cstdint>
#include <cstddef>

#define NH 8
#define LQ 2048
#define DH 64
#define NKT_HALF 16   // split-k: each block does 16 of the 32 k-tiles

typedef __attribute__((ext_vector_type(8))) __bf16 bf16x8;
typedef __attribute__((ext_vector_type(8))) unsigned short ushort8;
typedef __attribute__((ext_vector_type(4))) float floatx4;

__device__ __forceinline__ unsigned short bf_trunc(float x) {
    return (unsigned short)(__float_as_uint(x) >> 16);
}
__device__ __forceinline__ float bf_up(unsigned short h) {
    return __uint_as_float(((unsigned int)h) << 16);
}
__device__ __forceinline__ unsigned short bf_rne(float x) {
    unsigned int u = __float_as_uint(x);
    return (unsigned short)((u + 0x7FFFu + ((u >> 16) & 1u)) >> 16);
}
struct hl_t { unsigned short h, l; };
// x ~= h + l with |x-h-l| <= 2^-16 |x|
__device__ __forceinline__ hl_t split2(float x) {
    hl_t r;
    r.h = bf_trunc(x);
    r.l = bf_trunc(x - bf_up(r.h));
    return r;
}

#define MFMA16(A, B, C) __builtin_amdgcn_mfma_f32_16x16x32_bf16((A), (B), (C), 0, 0, 0)

// ---------------------------------------------------------------------------
// prep_kernel: one-shot conversion pass. Moves ALL split2/transpose/meta math
// out of the 32x-redundant hot loop.
//   bid <  256: K -> khig/klog, pre-scaled by 0.125 (exact), layout [h][k][64] bf16
//   bid <  512: V -> vhig/vlog, c-folded, TRANSPOSED per 64-tile: [h][kt][d][64]
//   bid >= 512: meta[h][k][12] folded bias coefficients
// ---------------------------------------------------------------------------
__global__ __launch_bounds__(256) void prep_kernel(
    const float* __restrict__ kp,  const float* __restrict__ vp,
    const float* __restrict__ cp,  const float* __restrict__ dktp,
    const float* __restrict__ dkbp,const float* __restrict__ dksp,
    const float* __restrict__ Wwp, const float* __restrict__ Wbp,
    unsigned short* __restrict__ khig, unsigned short* __restrict__ klog,
    unsigned short* __restrict__ vhig, unsigned short* __restrict__ vlog,
    float* __restrict__ metag)
{
    const int bid = blockIdx.x;
    const int t   = threadIdx.x;

    if (bid < 256) {
        // ---- K: scale by 0.125 (exact pow2), split, store hi/lo bf16 ----
        const int h = bid >> 5, kt = bid & 31;
        const int row = t >> 2, s = t & 3;
        const size_t kg = (size_t)(h * LQ) + kt * 64 + row;
        const float* src = kp + kg * DH + s * 16;
        unsigned short* dh_ = khig + kg * DH + s * 16;
        unsigned short* dl_ = klog + kg * DH + s * 16;
        ushort8 vh0, vh1, vl0, vl1;
#pragma unroll
        for (int j = 0; j < 2; ++j) {
            float4 x = *(const float4*)(src + 4 * j);
            hl_t a = split2(x.x * 0.125f), b = split2(x.y * 0.125f);
            hl_t c = split2(x.z * 0.125f), d = split2(x.w * 0.125f);
            vh0[4*j+0]=a.h; vl0[4*j+0]=a.l; vh0[4*j+1]=b.h; vl0[4*j+1]=b.l;
            vh0[4*j+2]=c.h; vl0[4*j+2]=c.l; vh0[4*j+3]=d.h; vl0[4*j+3]=d.l;
        }
#pragma unroll
        for (int j = 0; j < 2; ++j) {
            float4 x = *(const float4*)(src + 8 + 4 * j);
            hl_t a = split2(x.x * 0.125f), b = split2(x.y * 0.125f);
            hl_t c = split2(x.z * 0.125f), d = split2(x.w * 0.125f);
            vh1[4*j+0]=a.h; vl1[4*j+0]=a.l; vh1[4*j+1]=b.h; vl1[4*j+1]=b.l;
            vh1[4*j+2]=c.h; vl1[4*j+2]=c.l; vh1[4*j+3]=d.h; vl1[4*j+3]=d.l;
        }
        *(ushort8*)&dh_[0] = vh0; *(ushort8*)&dh_[8] = vh1;
        *(ushort8*)&dl_[0] = vl0; *(ushort8*)&dl_[8] = vl1;
    } else if (bid < 512) {
        // ---- V: transpose per 64-tile, fold c, split, packed uint stores ----
        const int h = (bid - 256) >> 5, kt = (bid - 256) & 31;
        const int p = t >> 4, mm = t & 15;
        const int k0 = kt * 64;
#pragma unroll
        for (int g = 0; g < 2; ++g) {
            const int kka = 2 * p + 32 * g;
            const float ca = cp[k0 + kka], cb = cp[k0 + kka + 1];
            const float* va = vp + ((size_t)(h * LQ + k0 + kka)) * DH;
            const float* vb = va + DH;
#pragma unroll
            for (int dd = 0; dd < 4; ++dd) {
                const int d = mm + 16 * dd;
                hl_t xa = split2(va[d] * ca);
                hl_t xb = split2(vb[d] * cb);
                const size_t base = ((size_t)(h * 32 + kt) * 64 + d) * 64 + kka;
                *(unsigned int*)&vhig[base] = (unsigned int)xa.h | ((unsigned int)xb.h << 16);
                *(unsigned int*)&vlog[base] = (unsigned int)xa.l | ((unsigned int)xb.l << 16);
            }
        }
    } else {
        // ---- meta: folded bias coefficients per (h,k) ----
        const int idx = (bid - 512) * 256 + t;    // 0..16383
        const int h  = idx >> 11;
        const int kg = idx & 2047;
        float Ww[4], Wb[4];
#pragma unroll
        for (int f = 0; f < 4; ++f) { Ww[f] = Wwp[f * NH + h]; Wb[f] = Wbp[f * NH + h]; }
        const float* sc_ = dksp + (size_t)kg * 8;   // [2][4] top then bottom
        const float* tp  = dktp + (size_t)kg * 3;
        const float* bt  = dkbp + (size_t)kg * 3;
        float* mo = metag + ((size_t)(h * LQ) + kg) * 12;
        float cw = 0.f, cb2 = 0.f;
#pragma unroll
        for (int f = 0; f < 3; ++f) {
            const float stf = sc_[f], sbf = sc_[4 + f];
            const float A  = stf + sbf;
            const float Bv = tp[f] * stf + bt[f] * sbf;
            mo[f]     = A * Ww[f];
            mo[4 + f] = A * Wb[f];
            cw  -= Bv * Ww[f];
            cb2 -= Bv * Wb[f];
        }
        mo[3]  = cw;              mo[7]  = cb2;
        mo[8]  = sc_[3] * Ww[3];  mo[9]  = sc_[7] * Ww[3];
        mo[10] = sc_[3] * Wb[3];  mo[11] = sc_[7] * Wb[3];
    }
}

// ---------------------------------------------------------------------------
// attn_main. Grid: 512 = 32 qt * 8 h * 2 half. Block: 256 thr (4 waves).
// PRE=1: staging is pure ushort8/float4 copies from the prep buffers
//        (K pre-scaled 0.125, V pre-transposed + c-folded, meta pre-folded).
// PRE=0: fallback = original in-kernel conversion (used if ws too small).
// NSPLIT fixed at 2: rounds 1/3 proved more blocks/occupancy never helps.
// ---------------------------------------------------------------------------
template<int PRE>
__global__ __launch_bounds__(256, 3) void attn_main(
    const float* __restrict__ qp,  const float* __restrict__ kp,
    const float* __restrict__ vp,  const float* __restrict__ cp,
    const float* __restrict__ dqp, const float* __restrict__ dktp,
    const float* __restrict__ dkbp,const float* __restrict__ dksp,
    const float* __restrict__ rtp, const float* __restrict__ rbp,
    const float* __restrict__ Wwp, const float* __restrict__ Wbp,
    const unsigned short* __restrict__ khig, const unsigned short* __restrict__ klog,
    const unsigned short* __restrict__ vhig, const unsigned short* __restrict__ vlog,
    const float* __restrict__ metag,
    float* __restrict__ probp, float* __restrict__ lws, float* __restrict__ pvws)
{
    __shared__ unsigned short sh_khi[64 * 72];   // Q-hi staging, then K-hi
    __shared__ unsigned short sh_klo[64 * 72];   // Q-lo staging, then K-lo, then ebf
    __shared__ unsigned short sh_vhi[64 * 72];   // V^T hi (c folded in)
    __shared__ unsigned short sh_vlo[64 * 72];   // V^T lo
    __shared__ float sh_meta[64 * 12];
    __shared__ float sh_dqs[64 * 3];

    const int bid  = blockIdx.x;
    const int half = bid & 1;
    const int h    = (bid >> 1) & 7;
    const int qt   = bid >> 4;
    const int q0   = qt * 64;
    const int t    = threadIdx.x;
    const int lane = t & 63;
    const int m    = lane & 15;
    const int quad = lane >> 4;
    const int w16  = (t >> 6) * 16;

    float Ww[4], Wb[4];
    if constexpr (!PRE) {
#pragma unroll
        for (int f = 0; f < 4; ++f) { Ww[f] = Wwp[f * NH + h]; Wb[f] = Wbp[f * NH + h]; }
    }

    // ---- stage Q (hi/lo) into the K buffers, load dqs (once per block) ----
    {
        const int row = t >> 2, s = t & 3;
        const float* src = qp + ((size_t)(h * LQ + q0 + row)) * DH + s * 16;
        ushort8 vh0, vh1, vl0, vl1;
#pragma unroll
        for (int j = 0; j < 2; ++j) {
            float4 x = *(const float4*)(src + 4 * j);
            hl_t a = split2(x.x), b = split2(x.y), c = split2(x.z), d = split2(x.w);
            vh0[4*j+0]=a.h; vl0[4*j+0]=a.l; vh0[4*j+1]=b.h; vl0[4*j+1]=b.l;
            vh0[4*j+2]=c.h; vl0[4*j+2]=c.l; vh0[4*j+3]=d.h; vl0[4*j+3]=d.l;
        }
#pragma unroll
        for (int j = 0; j < 2; ++j) {
            float4 x = *(const float4*)(src + 8 + 4 * j);
            hl_t a = split2(x.x), b = split2(x.y), c = split2(x.z), d = split2(x.w);
            vh1[4*j+0]=a.h; vl1[4*j+0]=a.l; vh1[4*j+1]=b.h; vl1[4*j+1]=b.l;
            vh1[4*j+2]=c.h; vl1[4*j+2]=c.l; vh1[4*j+3]=d.h; vl1[4*j+3]=d.l;
        }
        const int base = row * 72 + s * 16;
        *(ushort8*)&sh_khi[base] = vh0;  *(ushort8*)&sh_khi[base + 8] = vh1;
        *(ushort8*)&sh_klo[base] = vl0;  *(ushort8*)&sh_klo[base + 8] = vl1;
        if (t < 64) {
            sh_dqs[t * 3 + 0] = dqp[(q0 + t) * 3 + 0];
            sh_dqs[t * 3 + 1] = dqp[(q0 + t) * 3 + 1];
            sh_dqs[t * 3 + 2] = dqp[(q0 + t) * 3 + 2];
        }
    }
    __syncthreads();

    // Q A-fragments live in registers for the whole kernel
    bf16x8 aqh[2], aql[2];
#pragma unroll
    for (int kc = 0; kc < 2; ++kc) {
        aqh[kc] = *(const bf16x8*)&sh_khi[(w16 + m) * 72 + kc * 32 + quad * 8];
        aql[kc] = *(const bf16x8*)&sh_klo[(w16 + m) * 72 + kc * 32 + quad * 8];
    }
    float dq0[4], dq1[4], dq2[4];
#pragma unroll
    for (int r = 0; r < 4; ++r) {
        const int row = w16 + quad * 4 + r;
        dq0[r] = sh_dqs[row * 3 + 0]; dq1[r] = sh_dqs[row * 3 + 1]; dq2[r] = sh_dqs[row * 3 + 2];
    }
    __syncthreads();   // Q buffers free for K staging

    const floatx4 zf = {0.f, 0.f, 0.f, 0.f};
    floatx4 pacc[4] = {zf, zf, zf, zf};
    float lpart[4] = {0.f, 0.f, 0.f, 0.f};

    for (int kth = 0; kth < NKT_HALF; ++kth) {
        const int k0 = (half * NKT_HALF + kth) * 64;

        if constexpr (PRE) {
            // ---- K stage: pure copies (pre-scaled, pre-split) ----
            {
                const int row = t >> 2, s = t & 3;
                const size_t gb = ((size_t)(h * LQ) + k0 + row) * DH + s * 16;
                const int base = row * 72 + s * 16;
                *(ushort8*)&sh_khi[base]     = *(const ushort8*)&khig[gb];
                *(ushort8*)&sh_khi[base + 8] = *(const ushort8*)&khig[gb + 8];
                *(ushort8*)&sh_klo[base]     = *(const ushort8*)&klog[gb];
                *(ushort8*)&sh_klo[base + 8] = *(const ushort8*)&klog[gb + 8];
            }
            // ---- V stage: pure copies (pre-transposed, c-folded) ----
            {
                const int row = t >> 2, s = t & 3;
                const size_t gb = ((size_t)(h * 32 + (k0 >> 6)) * 64 + row) * 64 + s * 16;
                const int base = row * 72 + s * 16;
                *(ushort8*)&sh_vhi[base]     = *(const ushort8*)&vhig[gb];
                *(ushort8*)&sh_vhi[base + 8] = *(const ushort8*)&vhig[gb + 8];
                *(ushort8*)&sh_vlo[base]     = *(const ushort8*)&vlog[gb];
                *(ushort8*)&sh_vlo[base + 8] = *(const ushort8*)&vlog[gb + 8];
            }
            // ---- meta stage: 3 float4 per k, 192 threads ----
            if (t < 192) {
                const int k = t / 3, j = t - k * 3;
                const float4 mv = *(const float4*)(metag + ((size_t)(h * LQ) + k0 + k) * 12 + j * 4);
                *(float4*)&sh_meta[k * 12 + j * 4] = mv;
            }
        } else {
            // ---- fallback: original in-kernel conversion paths ----
            {
                const int row = t >> 2, s = t & 3;
                const float* src = kp + ((size_t)(h * LQ + k0 + row)) * DH + s * 16;
                ushort8 vh0, vh1, vl0, vl1;
#pragma unroll
                for (int j = 0; j < 2; ++j) {
                    float4 x = *(const float4*)(src + 4 * j);
                    hl_t a = split2(x.x), b = split2(x.y), c = split2(x.z), d = split2(x.w);
                    vh0[4*j+0]=a.h; vl0[4*j+0]=a.l; vh0[4*j+1]=b.h; vl0[4*j+1]=b.l;
                    vh0[4*j+2]=c.h; vl0[4*j+2]=c.l; vh0[4*j+3]=d.h; vl0[4*j+3]=d.l;
                }
#pragma unroll
                for (int j = 0; j < 2; ++j) {
                    float4 x = *(const float4*)(src + 8 + 4 * j);
                    hl_t a = split2(x.x), b = split2(x.y), c = split2(x.z), d = split2(x.w);
                    vh1[4*j+0]=a.h; vl1[4*j+0]=a.l; vh1[4*j+1]=b.h; vl1[4*j+1]=b.l;
                    vh1[4*j+2]=c.h; vl1[4*j+2]=c.l; vh1[4*j+3]=d.h; vl1[4*j+3]=d.l;
                }
                const int base = row * 72 + s * 16;
                *(ushort8*)&sh_khi[base] = vh0;  *(ushort8*)&sh_khi[base + 8] = vh1;
                *(ushort8*)&sh_klo[base] = vl0;  *(ushort8*)&sh_klo[base + 8] = vl1;
            }
            {
                const int p = t >> 4;
                const int mm = t & 15;
#pragma unroll
                for (int g = 0; g < 2; ++g) {
                    const int kka = 2 * p + 32 * g;
                    const float ca = cp[k0 + kka], cb = cp[k0 + kka + 1];
                    const float* va = vp + ((size_t)(h * LQ + k0 + kka)) * DH;
                    const float* vb = va + DH;
#pragma unroll
                    for (int dd = 0; dd < 4; ++dd) {
                        const int d = mm + 16 * dd;
                        hl_t xa = split2(va[d] * ca);
                        hl_t xb = split2(vb[d] * cb);
                        *(unsigned int*)&sh_vhi[d * 72 + kka] = (unsigned int)xa.h | ((unsigned int)xb.h << 16);
                        *(unsigned int*)&sh_vlo[d * 72 + kka] = (unsigned int)xa.l | ((unsigned int)xb.l << 16);
                    }
                }
            }
            if (t < 64) {
                const int kg = k0 + t;
                const float* sc_ = dksp + (size_t)kg * 8;
                const float* tp  = dktp + (size_t)kg * 3;
                const float* bt  = dkbp + (size_t)kg * 3;
                float cw = 0.f, cb2 = 0.f;
#pragma unroll
                for (int f = 0; f < 3; ++f) {
                    const float stf = sc_[f], sbf = sc_[4 + f];
                    const float A  = stf + sbf;
                    const float Bv = tp[f] * stf + bt[f] * sbf;
                    sh_meta[t * 12 + f]     = A * Ww[f];
                    sh_meta[t * 12 + 4 + f] = A * Wb[f];
                    cw  -= Bv * Ww[f];
                    cb2 -= Bv * Wb[f];
                }
                sh_meta[t * 12 + 3]  = cw;              sh_meta[t * 12 + 7]  = cb2;
                sh_meta[t * 12 + 8]  = sc_[3] * Ww[3];  sh_meta[t * 12 + 9]  = sc_[7] * Ww[3];
                sh_meta[t * 12 + 10] = sc_[3] * Wb[3];  sh_meta[t * 12 + 11] = sc_[7] * Wb[3];
            }
        }
        __syncthreads();

        // ---- prefetch rel features (hidden behind MFMA phase) ----
        float rt_[4][4], rb_[4][4];
#pragma unroll
        for (int r = 0; r < 4; ++r) {
            const size_t q = (size_t)(q0 + w16 + quad * 4 + r);
#pragma unroll
            for (int nt = 0; nt < 4; ++nt) {
                rt_[nt][r] = rtp[q * LQ + k0 + nt * 16 + m];
                rb_[nt][r] = rbp[q * LQ + k0 + nt * 16 + m];
            }
        }

        // ---- QK^T: 3-term split-bf16 MFMA ----
        floatx4 sc[4] = {zf, zf, zf, zf};
#pragma unroll
        for (int nt = 0; nt < 4; ++nt) {
#pragma unroll
            for (int kc = 0; kc < 2; ++kc) {
                const int kb = (nt * 16 + m) * 72 + kc * 32 + quad * 8;
                bf16x8 bh = *(const bf16x8*)&sh_khi[kb];
                bf16x8 bl = *(const bf16x8*)&sh_klo[kb];
                sc[nt] = MFMA16(aqh[kc], bh, sc[nt]);
                sc[nt] = MFMA16(aql[kc], bh, sc[nt]);
                sc[nt] = MFMA16(aqh[kc], bl, sc[nt]);
            }
        }
        __syncthreads();   // all waves done with K-lo -> reuse as ebf

        // ---- epilogue: gate + bias + exp; probs store; P->LDS ----
        unsigned short* ebf = sh_klo;
#pragma unroll
        for (int nt = 0; nt < 4; ++nt) {
            const int kcol = nt * 16 + m;
            const float m0 = sh_meta[kcol * 12 + 0],  m1 = sh_meta[kcol * 12 + 1];
            const float m2 = sh_meta[kcol * 12 + 2],  m3 = sh_meta[kcol * 12 + 3];
            const float m4 = sh_meta[kcol * 12 + 4],  m5 = sh_meta[kcol * 12 + 5];
            const float m6 = sh_meta[kcol * 12 + 6],  m7 = sh_meta[kcol * 12 + 7];
            const float m8 = sh_meta[kcol * 12 + 8],  m9 = sh_meta[kcol * 12 + 9];
            const float mA = sh_meta[kcol * 12 + 10], mB = sh_meta[kcol * 12 + 11];
#pragma unroll
            for (int r = 0; r < 4; ++r) {
                float ww = fmaf(dq0[r], m0, m3); ww = fmaf(dq1[r], m1, ww); ww = fmaf(dq2[r], m2, ww);
                ww = fmaf(rt_[nt][r], m8, ww);   ww = fmaf(rb_[nt][r], m9, ww);
                float bb = fmaf(dq0[r], m4, m7); bb = fmaf(dq1[r], m5, bb); bb = fmaf(dq2[r], m6, bb);
                bb = fmaf(rt_[nt][r], mA, bb);   bb = fmaf(rb_[nt][r], mB, bb);
                const float wg = fmaxf(ww, 0.f) + __logf(1.f + __expf(-fabsf(ww)));
                float sv;
                if constexpr (PRE) sv = fmaf(sc[nt][r], wg, bb);          // 0.125 folded into K
                else               sv = fmaf(sc[nt][r] * 0.125f, wg, bb);
                const float e  = __expf(sv - 8.0f);   // constant shift cancels in normalization
                lpart[r] += e;
                probp[((size_t)(h * LQ + q0 + w16 + quad * 4 + r)) * LQ + k0 + kcol] = e;
                ebf[(w16 + quad * 4 + r) * 72 + kcol] = bf_rne(e);
            }
        }

        // ---- PV: bf16 P x split-bf16 V (own-wave rows) ----
        bf16x8 ap0 = *(const bf16x8*)&ebf[(w16 + m) * 72 + quad * 8];
        bf16x8 ap1 = *(const bf16x8*)&ebf[(w16 + m) * 72 + 32 + quad * 8];
#pragma unroll
        for (int nt = 0; nt < 4; ++nt) {
            const int vb = (nt * 16 + m) * 72 + quad * 8;
            bf16x8 bh0 = *(const bf16x8*)&sh_vhi[vb];
            bf16x8 bl0 = *(const bf16x8*)&sh_vlo[vb];
            bf16x8 bh1 = *(const bf16x8*)&sh_vhi[vb + 32];
            bf16x8 bl1 = *(const bf16x8*)&sh_vlo[vb + 32];
            pacc[nt] = MFMA16(ap0, bh0, pacc[nt]);
            pacc[nt] = MFMA16(ap0, bl0, pacc[nt]);
            pacc[nt] = MFMA16(ap1, bh1, pacc[nt]);
            pacc[nt] = MFMA16(ap1, bl1, pacc[nt]);
        }
        __syncthreads();   // ebf/vT consumed before next staging
    }

    // ---- row-sum partials: reduce over the 16 m-lanes ----
#pragma unroll
    for (int off = 1; off < 16; off <<= 1) {
#pragma unroll
        for (int r = 0; r < 4; ++r) lpart[r] += __shfl_xor(lpart[r], off, 64);
    }
    if (m == 0) {
#pragma unroll
        for (int r = 0; r < 4; ++r)
            lws[half * (NH * LQ) + h * LQ + q0 + w16 + quad * 4 + r] = lpart[r];
    }
    // ---- PV partials to ws ----
#pragma unroll
    for (int nt = 0; nt < 4; ++nt) {
#pragma unroll
        for (int r = 0; r < 4; ++r) {
            const size_t row = (size_t)(h * LQ + q0 + w16 + quad * 4 + r);
            pvws[(size_t)half * (NH * LQ * DH) + row * DH + nt * 16 + m] = pacc[nt][r];
        }
    }
}

// out = (pv0 + pv1) / (l0 + l1)
__global__ void combine_kernel(const float* __restrict__ pvws, const float* __restrict__ lws,
                               float* __restrict__ outp)
{
    const int idx4 = blockIdx.x * 256 + threadIdx.x;   // 0..262143
    const int row  = idx4 >> 4;
    const int d4   = (idx4 & 15) * 4;
    const float4 a = *(const float4*)(pvws + (size_t)row * DH + d4);
    const float4 b = *(const float4*)(pvws + (size_t)(NH * LQ * DH) + (size_t)row * DH + d4);
    const float rl = 1.0f / (lws[row] + lws[NH * LQ + row]);
    *(float4*)(outp + (size_t)row * DH + d4) =
        make_float4((a.x + b.x) * rl, (a.y + b.y) * rl, (a.z + b.z) * rl, (a.w + b.w) * rl);
}

// probs[row][k] = e[row][k] * c[k] / l[row]
__global__ void norm_kernel(float* __restrict__ probp, const float* __restrict__ cp,
                            const float* __restrict__ lws)
{
    const int row = blockIdx.x;
    const float rl = 1.0f / (lws[row] + lws[NH * LQ + row]);
    float* p = probp + (size_t)row * LQ;
    const int t = threadIdx.x;
    float4 x0 = *(const float4*)(p + t * 4);
    float4 x1 = *(const float4*)(p + (t + 256) * 4);
    const float4 c0 = *(const float4*)(cp + t * 4);
    const float4 c1 = *(const float4*)(cp + (t + 256) * 4);
    x0.x *= rl * c0.x; x0.y *= rl * c0.y; x0.z *= rl * c0.z; x0.w *= rl * c0.w;
    x1.x *= rl * c1.x; x1.y *= rl * c1.y; x1.z *= rl * c1.z; x1.w *= rl * c1.w;
    *(float4*)(p + t * 4)         = x0;
    *(float4*)(p + (t + 256) * 4) = x1;
}

extern "C" void kernel_launch(void* const* d_in, const int* in_sizes, int n_in,
                              void* d_out, int out_size, void* d_ws, size_t ws_size,
                              hipStream_t stream)
{
    (void)in_sizes; (void)n_in; (void)out_size;
    const float* qp   = (const float*)d_in[0];
    const float* kp   = (const float*)d_in[1];
    const float* vp   = (const float*)d_in[2];
    const float* cp   = (const float*)d_in[3];
    const float* dqp  = (const float*)d_in[4];
    const float* dktp = (const float*)d_in[5];
    const float* dkbp = (const float*)d_in[6];
    const float* dksp = (const float*)d_in[7];
    const float* rtp  = (const float*)d_in[8];
    const float* rbp  = (const float*)d_in[9];
    const float* Wwp  = (const float*)d_in[10];
    const float* Wbp  = (const float*)d_in[11];

    float* outp  = (float*)d_out;                            // [1,8,2048,64]
    float* probp = (float*)d_out + (size_t)NH * LQ * DH;     // [1,8,2048,2048]

    // Workspace layout:
    //   lws   [2][NH*LQ]            f32
    //   pvws  [2][NH*LQ*DH]         f32
    //   khig/klog/vhig/vlog [NH*LQ*DH] bf16 each
    //   metag [NH*LQ*12]            f32
    float* lws  = (float*)d_ws;
    float* pvws = lws + 2 * (NH * LQ);
    unsigned short* khig = (unsigned short*)(pvws + (size_t)2 * NH * LQ * DH);
    unsigned short* klog = khig + (size_t)NH * LQ * DH;
    unsigned short* vhig = klog + (size_t)NH * LQ * DH;
    unsigned short* vlog = vhig + (size_t)NH * LQ * DH;
    float* metag = (float*)(vlog + (size_t)NH * LQ * DH);

    const size_t need = (size_t)2 * NH * LQ * 4
                      + (size_t)2 * NH * LQ * DH * 4
                      + (size_t)4 * NH * LQ * DH * 2
                      + (size_t)NH * LQ * 12 * 4;   // ~17.7 MB

    if (ws_size >= need) {
        prep_kernel<<<dim3(576), dim3(256), 0, stream>>>(
            kp, vp, cp, dktp, dkbp, dksp, Wwp, Wbp, khig, klog, vhig, vlog, metag);
        attn_main<1><<<dim3(512), dim3(256), 0, stream>>>(
            qp, kp, vp, cp, dqp, dktp, dkbp, dksp, rtp, rbp, Wwp, Wbp,
            khig, klog, vhig, vlog, metag, probp, lws, pvws);
    } else {
        attn_main<0><<<dim3(512), dim3(256), 0, stream>>>(
            qp, kp, vp, cp, dqp, dktp, dkbp, dksp, rtp, rbp, Wwp, Wbp,
            nullptr, nullptr, nullptr, nullptr, nullptr, probp, lws, pvws);
    }
    combine_kernel<<<dim3(1024), dim3(256), 0, stream>>>(pvws, lws, outp);
    norm_kernel<<<dim3(NH * LQ), dim3(256), 0, stream>>>(probp, cp, lws);
}

// Round 5
// 286.156 us; speedup vs baseline: 1.6617x; 1.0040x over previous
//
#include <hip/hip_runtime.h>
#include <cstdint>
#include <cstddef>

#define NH 8
#define LQ 2048
#define DH 64
#define NKT_HALF 16   // split-k: each block does 16 of the 32 k-tiles

typedef __attribute__((ext_vector_type(8))) __bf16 bf16x8;
typedef __attribute__((ext_vector_type(8))) unsigned short ushort8;
typedef __attribute__((ext_vector_type(4))) float floatx4;

__device__ __forceinline__ unsigned short bf_trunc(float x) {
    return (unsigned short)(__float_as_uint(x) >> 16);
}
__device__ __forceinline__ float bf_up(unsigned short h) {
    return __uint_as_float(((unsigned int)h) << 16);
}
__device__ __forceinline__ unsigned short bf_rne(float x) {
    unsigned int u = __float_as_uint(x);
    return (unsigned short)((u + 0x7FFFu + ((u >> 16) & 1u)) >> 16);
}
struct hl_t { unsigned short h, l; };
// x ~= h + l with |x-h-l| <= 2^-16 |x|
__device__ __forceinline__ hl_t split2(float x) {
    hl_t r;
    r.h = bf_trunc(x);
    r.l = bf_trunc(x - bf_up(r.h));
    return r;
}

#define MFMA16(A, B, C) __builtin_amdgcn_mfma_f32_16x16x32_bf16((A), (B), (C), 0, 0, 0)

// ---------------------------------------------------------------------------
// prep_kernel: one-shot conversion pass (proven R4). K pre-scaled 0.125,
// V pre-transposed + c-folded, meta pre-folded. Hot loop stages pure copies.
// ---------------------------------------------------------------------------
__global__ __launch_bounds__(256) void prep_kernel(
    const float* __restrict__ kp,  const float* __restrict__ vp,
    const float* __restrict__ cp,  const float* __restrict__ dktp,
    const float* __restrict__ dkbp,const float* __restrict__ dksp,
    const float* __restrict__ Wwp, const float* __restrict__ Wbp,
    unsigned short* __restrict__ khig, unsigned short* __restrict__ klog,
    unsigned short* __restrict__ vhig, unsigned short* __restrict__ vlog,
    float* __restrict__ metag)
{
    const int bid = blockIdx.x;
    const int t   = threadIdx.x;

    if (bid < 256) {
        const int h = bid >> 5, kt = bid & 31;
        const int row = t >> 2, s = t & 3;
        const size_t kg = (size_t)(h * LQ) + kt * 64 + row;
        const float* src = kp + kg * DH + s * 16;
        unsigned short* dh_ = khig + kg * DH + s * 16;
        unsigned short* dl_ = klog + kg * DH + s * 16;
        ushort8 vh0, vh1, vl0, vl1;
#pragma unroll
        for (int j = 0; j < 2; ++j) {
            float4 x = *(const float4*)(src + 4 * j);
            hl_t a = split2(x.x * 0.125f), b = split2(x.y * 0.125f);
            hl_t c = split2(x.z * 0.125f), d = split2(x.w * 0.125f);
            vh0[4*j+0]=a.h; vl0[4*j+0]=a.l; vh0[4*j+1]=b.h; vl0[4*j+1]=b.l;
            vh0[4*j+2]=c.h; vl0[4*j+2]=c.l; vh0[4*j+3]=d.h; vl0[4*j+3]=d.l;
        }
#pragma unroll
        for (int j = 0; j < 2; ++j) {
            float4 x = *(const float4*)(src + 8 + 4 * j);
            hl_t a = split2(x.x * 0.125f), b = split2(x.y * 0.125f);
            hl_t c = split2(x.z * 0.125f), d = split2(x.w * 0.125f);
            vh1[4*j+0]=a.h; vl1[4*j+0]=a.l; vh1[4*j+1]=b.h; vl1[4*j+1]=b.l;
            vh1[4*j+2]=c.h; vl1[4*j+2]=c.l; vh1[4*j+3]=d.h; vl1[4*j+3]=d.l;
        }
        *(ushort8*)&dh_[0] = vh0; *(ushort8*)&dh_[8] = vh1;
        *(ushort8*)&dl_[0] = vl0; *(ushort8*)&dl_[8] = vl1;
    } else if (bid < 512) {
        const int h = (bid - 256) >> 5, kt = (bid - 256) & 31;
        const int p = t >> 4, mm = t & 15;
        const int k0 = kt * 64;
#pragma unroll
        for (int g = 0; g < 2; ++g) {
            const int kka = 2 * p + 32 * g;
            const float ca = cp[k0 + kka], cb = cp[k0 + kka + 1];
            const float* va = vp + ((size_t)(h * LQ + k0 + kka)) * DH;
            const float* vb = va + DH;
#pragma unroll
            for (int dd = 0; dd < 4; ++dd) {
                const int d = mm + 16 * dd;
                hl_t xa = split2(va[d] * ca);
                hl_t xb = split2(vb[d] * cb);
                const size_t base = ((size_t)(h * 32 + kt) * 64 + d) * 64 + kka;
                *(unsigned int*)&vhig[base] = (unsigned int)xa.h | ((unsigned int)xb.h << 16);
                *(unsigned int*)&vlog[base] = (unsigned int)xa.l | ((unsigned int)xb.l << 16);
            }
        }
    } else {
        const int idx = (bid - 512) * 256 + t;    // 0..16383
        const int h  = idx >> 11;
        const int kg = idx & 2047;
        float Ww[4], Wb[4];
#pragma unroll
        for (int f = 0; f < 4; ++f) { Ww[f] = Wwp[f * NH + h]; Wb[f] = Wbp[f * NH + h]; }
        const float* sc_ = dksp + (size_t)kg * 8;   // [2][4] top then bottom
        const float* tp  = dktp + (size_t)kg * 3;
        const float* bt  = dkbp + (size_t)kg * 3;
        float* mo = metag + ((size_t)(h * LQ) + kg) * 12;
        float cw = 0.f, cb2 = 0.f;
#pragma unroll
        for (int f = 0; f < 3; ++f) {
            const float stf = sc_[f], sbf = sc_[4 + f];
            const float A  = stf + sbf;
            const float Bv = tp[f] * stf + bt[f] * sbf;
            mo[f]     = A * Ww[f];
            mo[4 + f] = A * Wb[f];
            cw  -= Bv * Ww[f];
            cb2 -= Bv * Wb[f];
        }
        mo[3]  = cw;              mo[7]  = cb2;
        mo[8]  = sc_[3] * Ww[3];  mo[9]  = sc_[7] * Ww[3];
        mo[10] = sc_[3] * Wb[3];  mo[11] = sc_[7] * Wb[3];
    }
}

// ---------------------------------------------------------------------------
// attn_main. Grid: 512 = 32 qt * 8 h * 2 half. Block: 256 thr (4 waves).
// T14 async staging: tile t+1 K/V/meta are global-loaded into REGISTERS right
// after the staging barrier of tile t (latency hides under QK+epilogue+PV);
// the reg->LDS ds_writes happen at the top of the next iteration.
// __launch_bounds__(256,2): unified VGPR/AGPR budget 256/wave; grid gives
// 2 blocks/CU (8 waves/CU) regardless, so no occupancy loss; (256,3)'s ~170
// cap would spill with the +36 staging registers (R1 lesson: spills cost 16%).
// ---------------------------------------------------------------------------
__global__ __launch_bounds__(256, 2) void attn_main(
    const float* __restrict__ qp,  const float* __restrict__ dqp,
    const float* __restrict__ rtp, const float* __restrict__ rbp,
    const unsigned short* __restrict__ khig, const unsigned short* __restrict__ klog,
    const unsigned short* __restrict__ vhig, const unsigned short* __restrict__ vlog,
    const float* __restrict__ metag,
    float* __restrict__ probp, float* __restrict__ lws, float* __restrict__ pvws)
{
    __shared__ unsigned short sh_khi[64 * 72];   // Q-hi staging, then K-hi
    __shared__ unsigned short sh_klo[64 * 72];   // Q-lo staging, then K-lo, then ebf
    __shared__ unsigned short sh_vhi[64 * 72];   // V^T hi (c folded in)
    __shared__ unsigned short sh_vlo[64 * 72];   // V^T lo
    __shared__ float sh_meta[64 * 12];
    __shared__ float sh_dqs[64 * 3];

    const int bid  = blockIdx.x;
    const int half = bid & 1;
    const int h    = (bid >> 1) & 7;
    const int qt   = bid >> 4;
    const int q0   = qt * 64;
    const int t    = threadIdx.x;
    const int lane = t & 63;
    const int m    = lane & 15;
    const int quad = lane >> 4;
    const int w16  = (t >> 6) * 16;

    // staging thread mapping (constant for whole kernel)
    const int srow = t >> 2, ss = t & 3;
    const int sbase = srow * 72 + ss * 16;
    const int mk = t / 3, mj = t - mk * 3;            // meta mapping, valid t<192

    // global cursors for tile 0 of this half
    size_t kgb = ((size_t)(h * LQ) + half * NKT_HALF * 64 + srow) * DH + ss * 16;
    size_t vgb = ((size_t)(h * 32 + half * NKT_HALF) * 64 + srow) * 64 + ss * 16;
    size_t mgb = ((size_t)(h * LQ) + half * NKT_HALF * 64 + mk) * 12 + mj * 4;

    // ---- issue tile-0 staged loads immediately (hide under Q prologue) ----
    ushort8 rkh0 = *(const ushort8*)&khig[kgb];
    ushort8 rkh1 = *(const ushort8*)&khig[kgb + 8];
    ushort8 rkl0 = *(const ushort8*)&klog[kgb];
    ushort8 rkl1 = *(const ushort8*)&klog[kgb + 8];
    ushort8 rvh0 = *(const ushort8*)&vhig[vgb];
    ushort8 rvh1 = *(const ushort8*)&vhig[vgb + 8];
    ushort8 rvl0 = *(const ushort8*)&vlog[vgb];
    ushort8 rvl1 = *(const ushort8*)&vlog[vgb + 8];
    float4  rmeta;
    if (t < 192) rmeta = *(const float4*)&metag[mgb];

    // ---- stage Q (hi/lo) into the K buffers, load dqs (once per block) ----
    {
        const float* src = qp + ((size_t)(h * LQ + q0 + srow)) * DH + ss * 16;
        ushort8 vh0, vh1, vl0, vl1;
#pragma unroll
        for (int j = 0; j < 2; ++j) {
            float4 x = *(const float4*)(src + 4 * j);
            hl_t a = split2(x.x), b = split2(x.y), c = split2(x.z), d = split2(x.w);
            vh0[4*j+0]=a.h; vl0[4*j+0]=a.l; vh0[4*j+1]=b.h; vl0[4*j+1]=b.l;
            vh0[4*j+2]=c.h; vl0[4*j+2]=c.l; vh0[4*j+3]=d.h; vl0[4*j+3]=d.l;
        }
#pragma unroll
        for (int j = 0; j < 2; ++j) {
            float4 x = *(const float4*)(src + 8 + 4 * j);
            hl_t a = split2(x.x), b = split2(x.y), c = split2(x.z), d = split2(x.w);
            vh1[4*j+0]=a.h; vl1[4*j+0]=a.l; vh1[4*j+1]=b.h; vl1[4*j+1]=b.l;
            vh1[4*j+2]=c.h; vl1[4*j+2]=c.l; vh1[4*j+3]=d.h; vl1[4*j+3]=d.l;
        }
        *(ushort8*)&sh_khi[sbase] = vh0;  *(ushort8*)&sh_khi[sbase + 8] = vh1;
        *(ushort8*)&sh_klo[sbase] = vl0;  *(ushort8*)&sh_klo[sbase + 8] = vl1;
        if (t < 64) {
            sh_dqs[t * 3 + 0] = dqp[(q0 + t) * 3 + 0];
            sh_dqs[t * 3 + 1] = dqp[(q0 + t) * 3 + 1];
            sh_dqs[t * 3 + 2] = dqp[(q0 + t) * 3 + 2];
        }
    }
    __syncthreads();

    // Q A-fragments live in registers for the whole kernel
    bf16x8 aqh[2], aql[2];
#pragma unroll
    for (int kc = 0; kc < 2; ++kc) {
        aqh[kc] = *(const bf16x8*)&sh_khi[(w16 + m) * 72 + kc * 32 + quad * 8];
        aql[kc] = *(const bf16x8*)&sh_klo[(w16 + m) * 72 + kc * 32 + quad * 8];
    }
    float dq0[4], dq1[4], dq2[4];
#pragma unroll
    for (int r = 0; r < 4; ++r) {
        const int row = w16 + quad * 4 + r;
        dq0[r] = sh_dqs[row * 3 + 0]; dq1[r] = sh_dqs[row * 3 + 1]; dq2[r] = sh_dqs[row * 3 + 2];
    }
    __syncthreads();   // Q buffers free for K staging

    const floatx4 zf = {0.f, 0.f, 0.f, 0.f};
    floatx4 pacc[4] = {zf, zf, zf, zf};
    float lpart[4] = {0.f, 0.f, 0.f, 0.f};

    for (int kth = 0; kth < NKT_HALF; ++kth) {
        const int k0 = (half * NKT_HALF + kth) * 64;

        // ---- STAGE_WRITE: reg -> LDS (tile kth; loads were issued last iter) ----
        *(ushort8*)&sh_khi[sbase]     = rkh0;
        *(ushort8*)&sh_khi[sbase + 8] = rkh1;
        *(ushort8*)&sh_klo[sbase]     = rkl0;
        *(ushort8*)&sh_klo[sbase + 8] = rkl1;
        *(ushort8*)&sh_vhi[sbase]     = rvh0;
        *(ushort8*)&sh_vhi[sbase + 8] = rvh1;
        *(ushort8*)&sh_vlo[sbase]     = rvl0;
        *(ushort8*)&sh_vlo[sbase + 8] = rvl1;
        if (t < 192) *(float4*)&sh_meta[mk * 12 + mj * 4] = rmeta;
        __syncthreads();   // B1: tile kth resident in LDS

        // ---- STAGE_LOAD: issue tile kth+1 global loads (hide under compute) ----
        if (kth + 1 < NKT_HALF) {
            kgb += (size_t)64 * DH;
            vgb += (size_t)64 * 64;
            mgb += (size_t)64 * 12;
            rkh0 = *(const ushort8*)&khig[kgb];
            rkh1 = *(const ushort8*)&khig[kgb + 8];
            rkl0 = *(const ushort8*)&klog[kgb];
            rkl1 = *(const ushort8*)&klog[kgb + 8];
            rvh0 = *(const ushort8*)&vhig[vgb];
            rvh1 = *(const ushort8*)&vhig[vgb + 8];
            rvl0 = *(const ushort8*)&vlog[vgb];
            rvl1 = *(const ushort8*)&vlog[vgb + 8];
            if (t < 192) rmeta = *(const float4*)&metag[mgb];
        }

        // ---- prefetch rel features (also hidden behind MFMA phase) ----
        float rt_[4][4], rb_[4][4];
#pragma unroll
        for (int r = 0; r < 4; ++r) {
            const size_t q = (size_t)(q0 + w16 + quad * 4 + r);
#pragma unroll
            for (int nt = 0; nt < 4; ++nt) {
                rt_[nt][r] = rtp[q * LQ + k0 + nt * 16 + m];
                rb_[nt][r] = rbp[q * LQ + k0 + nt * 16 + m];
            }
        }

        // ---- QK^T: 3-term split-bf16 MFMA (0.125 pre-folded into K) ----
        floatx4 sc[4] = {zf, zf, zf, zf};
#pragma unroll
        for (int nt = 0; nt < 4; ++nt) {
#pragma unroll
            for (int kc = 0; kc < 2; ++kc) {
                const int kb = (nt * 16 + m) * 72 + kc * 32 + quad * 8;
                bf16x8 bh = *(const bf16x8*)&sh_khi[kb];
                bf16x8 bl = *(const bf16x8*)&sh_klo[kb];
                sc[nt] = MFMA16(aqh[kc], bh, sc[nt]);
                sc[nt] = MFMA16(aql[kc], bh, sc[nt]);
                sc[nt] = MFMA16(aqh[kc], bl, sc[nt]);
            }
        }
        __syncthreads();   // B2: all waves done with K-lo -> reuse as ebf

        // ---- epilogue: gate + bias + exp; probs store; P->LDS ----
        unsigned short* ebf = sh_klo;
#pragma unroll
        for (int nt = 0; nt < 4; ++nt) {
            const int kcol = nt * 16 + m;
            const float m0 = sh_meta[kcol * 12 + 0],  m1 = sh_meta[kcol * 12 + 1];
            const float m2 = sh_meta[kcol * 12 + 2],  m3 = sh_meta[kcol * 12 + 3];
            const float m4 = sh_meta[kcol * 12 + 4],  m5 = sh_meta[kcol * 12 + 5];
            const float m6 = sh_meta[kcol * 12 + 6],  m7 = sh_meta[kcol * 12 + 7];
            const float m8 = sh_meta[kcol * 12 + 8],  m9 = sh_meta[kcol * 12 + 9];
            const float mA = sh_meta[kcol * 12 + 10], mB = sh_meta[kcol * 12 + 11];
#pragma unroll
            for (int r = 0; r < 4; ++r) {
                float ww = fmaf(dq0[r], m0, m3); ww = fmaf(dq1[r], m1, ww); ww = fmaf(dq2[r], m2, ww);
                ww = fmaf(rt_[nt][r], m8, ww);   ww = fmaf(rb_[nt][r], m9, ww);
                float bb = fmaf(dq0[r], m4, m7); bb = fmaf(dq1[r], m5, bb); bb = fmaf(dq2[r], m6, bb);
                bb = fmaf(rt_[nt][r], mA, bb);   bb = fmaf(rb_[nt][r], mB, bb);
                const float wg = fmaxf(ww, 0.f) + __logf(1.f + __expf(-fabsf(ww)));
                const float sv = fmaf(sc[nt][r], wg, bb);
                const float e  = __expf(sv - 8.0f);   // constant shift cancels in normalization
                lpart[r] += e;
                probp[((size_t)(h * LQ + q0 + w16 + quad * 4 + r)) * LQ + k0 + kcol] = e;
                ebf[(w16 + quad * 4 + r) * 72 + kcol] = bf_rne(e);
            }
        }

        // ---- PV: bf16 P x split-bf16 V (own-wave rows; no barrier before reads) ----
        bf16x8 ap0 = *(const bf16x8*)&ebf[(w16 + m) * 72 + quad * 8];
        bf16x8 ap1 = *(const bf16x8*)&ebf[(w16 + m) * 72 + 32 + quad * 8];
#pragma unroll
        for (int nt = 0; nt < 4; ++nt) {
            const int vb = (nt * 16 + m) * 72 + quad * 8;
            bf16x8 bh0 = *(const bf16x8*)&sh_vhi[vb];
            bf16x8 bl0 = *(const bf16x8*)&sh_vlo[vb];
            bf16x8 bh1 = *(const bf16x8*)&sh_vhi[vb + 32];
            bf16x8 bl1 = *(const bf16x8*)&sh_vlo[vb + 32];
            pacc[nt] = MFMA16(ap0, bh0, pacc[nt]);
            pacc[nt] = MFMA16(ap0, bl0, pacc[nt]);
            pacc[nt] = MFMA16(ap1, bh1, pacc[nt]);
            pacc[nt] = MFMA16(ap1, bl1, pacc[nt]);
        }
        __syncthreads();   // B3: ebf/vT consumed; next iter overwrites LDS
    }

    // ---- row-sum partials: reduce over the 16 m-lanes ----
#pragma unroll
    for (int off = 1; off < 16; off <<= 1) {
#pragma unroll
        for (int r = 0; r < 4; ++r) lpart[r] += __shfl_xor(lpart[r], off, 64);
    }
    if (m == 0) {
#pragma unroll
        for (int r = 0; r < 4; ++r)
            lws[half * (NH * LQ) + h * LQ + q0 + w16 + quad * 4 + r] = lpart[r];
    }
    // ---- PV partials to ws ----
#pragma unroll
    for (int nt = 0; nt < 4; ++nt) {
#pragma unroll
        for (int r = 0; r < 4; ++r) {
            const size_t row = (size_t)(h * LQ + q0 + w16 + quad * 4 + r);
            pvws[(size_t)half * (NH * LQ * DH) + row * DH + nt * 16 + m] = pacc[nt][r];
        }
    }
}

// ---------------------------------------------------------------------------
// norm_combine: probs[row][k] = e * c[k] / l[row]  AND  out = (pv0+pv1)/l.
// 2048 blocks x 8 rows: c loaded once per block into regs (reused 8x).
// ---------------------------------------------------------------------------
__global__ __launch_bounds__(256) void norm_combine(
    float* __restrict__ probp, const float* __restrict__ cp,
    const float* __restrict__ lws, const float* __restrict__ pvws,
    float* __restrict__ outp)
{
    __shared__ float rl8[8];
    const int t    = threadIdx.x;
    const int row0 = blockIdx.x * 8;
    const float4 c0 = *(const float4*)(cp + t * 4);
    const float4 c1 = *(const float4*)(cp + (t + 256) * 4);
    if (t < 8) rl8[t] = 1.0f / (lws[row0 + t] + lws[NH * LQ + row0 + t]);
    __syncthreads();
#pragma unroll 2
    for (int rr = 0; rr < 8; ++rr) {
        const float rl = rl8[rr];
        float* p = probp + (size_t)(row0 + rr) * LQ;
        float4 x0 = *(const float4*)(p + t * 4);
        float4 x1 = *(const float4*)(p + (t + 256) * 4);
        x0.x *= rl * c0.x; x0.y *= rl * c0.y; x0.z *= rl * c0.z; x0.w *= rl * c0.w;
        x1.x *= rl * c1.x; x1.y *= rl * c1.y; x1.z *= rl * c1.z; x1.w *= rl * c1.w;
        *(float4*)(p + t * 4)         = x0;
        *(float4*)(p + (t + 256) * 4) = x1;
    }
    // combine: 8 rows x 64 d = 512 outputs, 2 per thread
#pragma unroll
    for (int j = 0; j < 2; ++j) {
        const int lin = j * 256 + t;
        const int rr  = lin >> 6, d = lin & 63;
        const size_t rowd = (size_t)(row0 + rr) * DH + d;
        outp[rowd] = (pvws[rowd] + pvws[(size_t)(NH * LQ * DH) + rowd]) * rl8[rr];
    }
}

extern "C" void kernel_launch(void* const* d_in, const int* in_sizes, int n_in,
                              void* d_out, int out_size, void* d_ws, size_t ws_size,
                              hipStream_t stream)
{
    (void)in_sizes; (void)n_in; (void)out_size; (void)ws_size;
    const float* qp   = (const float*)d_in[0];
    const float* kp   = (const float*)d_in[1];
    const float* vp   = (const float*)d_in[2];
    const float* cp   = (const float*)d_in[3];
    const float* dqp  = (const float*)d_in[4];
    const float* dktp = (const float*)d_in[5];
    const float* dkbp = (const float*)d_in[6];
    const float* dksp = (const float*)d_in[7];
    const float* rtp  = (const float*)d_in[8];
    const float* rbp  = (const float*)d_in[9];
    const float* Wwp  = (const float*)d_in[10];
    const float* Wbp  = (const float*)d_in[11];

    float* outp  = (float*)d_out;                            // [1,8,2048,64]
    float* probp = (float*)d_out + (size_t)NH * LQ * DH;     // [1,8,2048,2048]

    // Workspace layout (17.7 MB, proven sufficient by R3/R4 runs taking PRE path):
    //   lws   [2][NH*LQ]            f32
    //   pvws  [2][NH*LQ*DH]         f32
    //   khig/klog/vhig/vlog [NH*LQ*DH] bf16 each
    //   metag [NH*LQ*12]            f32
    float* lws  = (float*)d_ws;
    float* pvws = lws + 2 * (NH * LQ);
    unsigned short* khig = (unsigned short*)(pvws + (size_t)2 * NH * LQ * DH);
    unsigned short* klog = khig + (size_t)NH * LQ * DH;
    unsigned short* vhig = klog + (size_t)NH * LQ * DH;
    unsigned short* vlog = vhig + (size_t)NH * LQ * DH;
    float* metag = (float*)(vlog + (size_t)NH * LQ * DH);

    prep_kernel<<<dim3(576), dim3(256), 0, stream>>>(
        kp, vp, cp, dktp, dkbp, dksp, Wwp, Wbp, khig, klog, vhig, vlog, metag);
    attn_main<<<dim3(512), dim3(256), 0, stream>>>(
        qp, dqp, rtp, rbp, khig, klog, vhig, vlog, metag, probp, lws, pvws);
    norm_combine<<<dim3(2048), dim3(256), 0, stream>>>(probp, cp, lws, pvws, outp);
}